// Round 7
// baseline (98.501 us; speedup 1.0000x reference)
//
#include <hip/hip_runtime.h>

typedef __fp16 half8_t __attribute__((ext_vector_type(8)));
typedef float  f4_t    __attribute__((ext_vector_type(4)));

__device__ __forceinline__ unsigned pk(float a, float b) {
    return __builtin_bit_cast(unsigned, __builtin_amdgcn_cvt_pkrtz(a, b));
}

// ---------------------------------------------------------------------------
// QKV fused: 1x1-conv via f16 MFMA (W staged as f16 A-frags in LDS once per
// block, x converted inline). Grid 768 = 3 matrices x 256 tile-groups; wave =
// 1 px-tile of 16, 32 MFMA. Output f16-packed [pos][c2]. q-blocks also emit
// relative-bias tables biasG[px][16] (j<7: bias_x[j], 7..13: bias_y[j-7]).
// LDS: transpose buffer aliased with group-sum buffer (sequential lifetimes)
// -> 38.4 KB -> 4 blocks/CU (launch_bounds(256,4)).
// ---------------------------------------------------------------------------
__global__ __launch_bounds__(256, 4) void qkv_fused(
    const float* __restrict__ x, const float* __restrict__ wq,
    const float* __restrict__ wk, const float* __restrict__ wv,
    const float* __restrict__ relx, const float* __restrict__ rely,
    unsigned* __restrict__ qf, unsigned* __restrict__ kf,
    unsigned* __restrict__ vf, float* __restrict__ biasG)
{
    __shared__ __fp16 Af[2048 * 8];          // 32 KB A-frags
    __shared__ float  uB[4][320];            // tl (272) / sS (320) aliased
    __shared__ float  relsQ[120];

    const int tid = threadIdx.x, wvn = tid >> 6, lane = tid & 63;
    const int mtx = blockIdx.x >> 8;         // 0=q 1=k 2=v
    const int tg  = blockIdx.x & 255;
    const float* wsrc = (mtx == 0) ? wq : (mtx == 1 ? wk : wv);
    unsigned*    dst  = (mtx == 0) ? qf : (mtx == 1 ? kf : vf);

    if (tid < 120)
        relsQ[tid] = (tid < 56) ? relx[tid] : (tid < 112 ? rely[tid - 56] : 0.f);

    // ---- stage W (128x128) as f16 A-frags ----
#pragma unroll
    for (int s = 0; s < 8; ++s) {
        const int it = s * 256 + tid;        // ((otile*4+ck)*64+l)
        const int l = it & 63, ck = (it >> 6) & 3, ot = it >> 8;
        const float* wr = wsrc + (size_t)(ot * 16 + (l & 15)) * 128 + ck * 32 + (l >> 4) * 8;
        const float4 w0 = *(const float4*)wr;
        const float4 w1 = *(const float4*)(wr + 4);
        unsigned* d = (unsigned*)&Af[it * 8];
        d[0] = pk(w0.x, w0.y); d[1] = pk(w0.z, w0.w);
        d[2] = pk(w1.x, w1.y); d[3] = pk(w1.z, w1.w);
    }

    // ---- B-frags: this wave's 16-px x-tile ----
    const int t = tg * 4 + wvn;
    const int m = lane & 15, quad = lane >> 4;
    const int p0 = t * 16, b = p0 >> 12, hw = p0 & 4095;
    const float* xb = x + (size_t)b * (128 * 4096) + hw + m;
    half8_t B[4];
#pragma unroll
    for (int ck = 0; ck < 4; ++ck) {
        float f[8];
#pragma unroll
        for (int j = 0; j < 8; ++j) f[j] = xb[(size_t)(ck * 32 + quad * 8 + j) * 4096];
        unsigned* d = (unsigned*)&B[ck];
        d[0] = pk(f[0], f[1]); d[1] = pk(f[2], f[3]);
        d[2] = pk(f[4], f[5]); d[3] = pk(f[6], f[7]);
    }
    __syncthreads();

    float* tl = uB[wvn];
    float s0 = 0.f, s1 = 0.f, s2 = 0.f, s3 = 0.f;   // group-sum partials
#pragma unroll
    for (int og = 0; og < 4; ++og) {
#pragma unroll
        for (int ot = 0; ot < 2; ++ot) {
            const int otile = og * 2 + ot;
            f4_t acc = {0.f, 0.f, 0.f, 0.f};
#pragma unroll
            for (int ck = 0; ck < 4; ++ck) {
                const half8_t A = *(const half8_t*)&Af[((otile * 4 + ck) * 64 + lane) * 8];
                acc = __builtin_amdgcn_mfma_f32_16x16x32_f16(A, B[ck], acc, 0, 0, 0);
            }
            if (mtx == 0) { s0 += acc[0]; s1 += acc[1]; s2 += acc[2]; s3 += acc[3]; }
            const int c2l = ot * 8 + quad * 2;
            tl[m * 17 + c2l]     = __builtin_bit_cast(float, pk(acc[0], acc[1]));
            tl[m * 17 + c2l + 1] = __builtin_bit_cast(float, pk(acc[2], acc[3]));
        }
        __asm__ volatile("s_waitcnt lgkmcnt(0)" ::: "memory");
        __builtin_amdgcn_wave_barrier();
#pragma unroll
        for (int s = 0; s < 4; ++s) {
            const int px = s * 4 + quad;
            dst[(size_t)(p0 + px) * 64 + og * 16 + m] =
                __builtin_bit_cast(unsigned, tl[px * 17 + m]);
        }
        __builtin_amdgcn_wave_barrier();
    }

    // ---- bias tables (q-blocks only): biasG[px][j] ----
    if (mtx == 0) {
        float* sS = uB[wvn];                            // alias (tl done)
        f4_t sv = {s0, s1, s2, s3};                     // t = quad*4 + e
        __asm__ volatile("s_waitcnt lgkmcnt(0)" ::: "memory");
        __builtin_amdgcn_wave_barrier();
        *(f4_t*)&sS[m * 20 + quad * 4] = sv;
        __asm__ volatile("s_waitcnt lgkmcnt(0)" ::: "memory");
        __builtin_amdgcn_wave_barrier();
        f4_t bj = {0.f, 0.f, 0.f, 0.f};
#pragma unroll
        for (int jj = 0; jj < 4; ++jj) {
            const int j = quad * 4 + jj;
            float s = 0.f;
            if (j < 7) {
#pragma unroll
                for (int tt = 0; tt < 8; ++tt)
                    s = fmaf(sS[m * 20 + tt], relsQ[tt * 7 + j], s);
            } else if (j < 14) {
#pragma unroll
                for (int tt = 0; tt < 8; ++tt)
                    s = fmaf(sS[m * 20 + 8 + tt], relsQ[56 + tt * 7 + (j - 7)], s);
            }
            bj[jj] = s;
        }
        *(f4_t*)(biasG + (size_t)(p0 + m) * 16 + quad * 4) = bj;
    }
}

// ---------------------------------------------------------------------------
// Attention: grid 512, block 256 = 4 waves; tile = 4 px-rows x 8 cols.
// Wave = 8 px (one row). Wave PAIR (rows r, r+1) shares one 8-row x 16-col
// k-window (k = kri*16+ci, 128 = 4 MFMA chunks) and one aW A-fragment:
//   QK: per wave 7 n-tiles (window row t, 16 cols) x 4 kc = 28 MFMA.
//       Q/K frags direct from global [pos][c2] (full 64B-line coalescing,
//       OOB exec-masked to 0 == reference zero-padding).
//   softmax in D-layout (kj = n - m, ki = t), weights f16 -> shared
//       aW[pair][row = u*8+m][k = (u+t)*16+ci]  (disjoint rows per wave).
//   PV: pair-cooperative, wave does 4 tn c-tiles x 4 kc = 16 MFMA; B from
//       vH[c][hi*16+ci] (pitch 168, 16B-aligned, ~2-way banks), fp32 D
//       stored direct to (B,C,H,W).
// LDS 53.8 KB -> 2 blocks/CU -> 2 waves/SIMD (2x round 6).
// ---------------------------------------------------------------------------
constexpr int VP = 168;   // vH pitch (f16)

__global__ __launch_bounds__(256) void attn_mfma(
    const unsigned* __restrict__ qf, const unsigned* __restrict__ kf,
    const unsigned* __restrict__ vf, const float* __restrict__ biasG,
    float* __restrict__ out)
{
    __shared__ __fp16 vH[128 * VP];          // 43,008 B
    __shared__ __fp16 aW[2][16 * 136];       //  8,704 B
    __shared__ float  biasL[32 * 16];        //  2,048 B

    const int tid = threadIdx.x, bx = blockIdx.x;
    const int wv = tid >> 6, lane = tid & 63;
    const int w0 = (bx & 7) * 8;
    const int h0 = ((bx >> 3) & 15) * 4;
    const int b  = bx >> 7;
    const int s  = wv >> 1, u = wv & 1;
    const int wr = h0 + 2 * s + u;           // this wave's px row
    const int n16 = lane & 15, quad = lane >> 4;

    // ---- zero aW (only rows/k-slots not later overwritten matter) ----
    for (int i = tid; i < 2176; i += 256) ((unsigned*)aW)[i] = 0u;

    // ---- stage V halo: vH[c][hi*16+ci], 10 rows x 16 cols, perm-transpose --
    {
        const int g = tid >> 3, r = tid & 7;     // g = c2-quad 0..31
#pragma unroll
        for (int it = 0; it < 5; ++it) {
            const int pq = r + 8 * it;           // 0..39
            const int hi = pq >> 2, ciq = pq & 3;
            const int py = h0 - 3 + hi;
            unsigned d0[4], d1[4];
#pragma unroll
            for (int p = 0; p < 4; ++p) {
                const int pxc = w0 - 3 + ciq * 4 + p;
                uint2 d = make_uint2(0u, 0u);
                if ((unsigned)py < 64u && (unsigned)pxc < 64u)
                    d = *(const uint2*)(vf + (size_t)((b * 4096 + py * 64 + pxc) * 64 + g * 2));
                d0[p] = d.x; d1[p] = d.y;
            }
            const int c0 = g * 4, off = hi * 16 + ciq * 4;
            *(uint2*)(vH + (c0 + 0) * VP + off) = make_uint2(
                __builtin_amdgcn_perm(d0[1], d0[0], 0x05040100u),
                __builtin_amdgcn_perm(d0[3], d0[2], 0x05040100u));
            *(uint2*)(vH + (c0 + 1) * VP + off) = make_uint2(
                __builtin_amdgcn_perm(d0[1], d0[0], 0x07060302u),
                __builtin_amdgcn_perm(d0[3], d0[2], 0x07060302u));
            *(uint2*)(vH + (c0 + 2) * VP + off) = make_uint2(
                __builtin_amdgcn_perm(d1[1], d1[0], 0x05040100u),
                __builtin_amdgcn_perm(d1[3], d1[2], 0x05040100u));
            *(uint2*)(vH + (c0 + 3) * VP + off) = make_uint2(
                __builtin_amdgcn_perm(d1[1], d1[0], 0x07060302u),
                __builtin_amdgcn_perm(d1[3], d1[2], 0x07060302u));
        }
    }

    // ---- bias tables for the block's 32 px ----
    for (int i = tid; i < 512; i += 256) {
        const int px = i >> 4, tt = i & 15;
        const int pix = b * 4096 + (h0 + (px >> 3)) * 64 + w0 + (px & 7);
        biasL[px * 16 + tt] = biasG[(size_t)pix * 16 + tt];
    }
    __syncthreads();

    // ---- Phase A: QK^T (wave = 8 px of row wr) ----
    uint4 qA[4];
    {
        const bool vm = n16 < 8;
        const size_t qb = (size_t)(b * 4096 + wr * 64 + w0 + n16) * 64;
#pragma unroll
        for (int kc = 0; kc < 4; ++kc) {
            uint4 t4 = make_uint4(0u, 0u, 0u, 0u);
            if (vm) t4 = *(const uint4*)(qf + qb + kc * 16 + quad * 4);
            qA[kc] = t4;
        }
    }
    f4_t lg[7];
#pragma unroll
    for (int t = 0; t < 7; ++t) {
        const int py = wr - 3 + t;
        const int pxc = w0 - 3 + n16;
        const bool val = ((unsigned)py < 64u) && ((unsigned)pxc < 64u);
        const size_t kb = (size_t)(b * 4096 + py * 64 + pxc) * 64;
        f4_t acc = {0.f, 0.f, 0.f, 0.f};
#pragma unroll
        for (int kc = 0; kc < 4; ++kc) {
            uint4 kB = make_uint4(0u, 0u, 0u, 0u);
            if (val) kB = *(const uint4*)(kf + kb + kc * 16 + quad * 4);
            acc = __builtin_amdgcn_mfma_f32_16x16x32_f16(
                __builtin_bit_cast(half8_t, qA[kc]),
                __builtin_bit_cast(half8_t, kB), acc, 0, 0, 0);
        }
        lg[t] = acc;
    }

    // ---- softmax per px (D-layout: col=ci=n16, row=px=quad*4+i) ----
    const int rowblk = 2 * s + u;
#pragma unroll
    for (int i = 0; i < 4; ++i) {
        const int m = quad * 4 + i;              // valid px: m < 8
        const float* bb = &biasL[(rowblk * 8 + (m & 7)) * 16];
        const int kj = n16 - m;
        const bool kv = (unsigned)kj < 7u;
        const float bx2 = kv ? bb[kj] : 0.f;
        float lv[7];
        float mx = -1e30f;
#pragma unroll
        for (int t = 0; t < 7; ++t) {
            const float v = kv ? lg[t][i] + bx2 + bb[7 + t] : -1e30f;
            lv[t] = v;
            mx = fmaxf(mx, v);
        }
        mx = fmaxf(mx, __shfl_xor(mx, 1));
        mx = fmaxf(mx, __shfl_xor(mx, 2));
        mx = fmaxf(mx, __shfl_xor(mx, 4));
        mx = fmaxf(mx, __shfl_xor(mx, 8));
        float ss = 0.f;
#pragma unroll
        for (int t = 0; t < 7; ++t) {
            const float e = __expf(lv[t] - mx);
            lv[t] = e;
            ss += e;
        }
        ss += __shfl_xor(ss, 1);
        ss += __shfl_xor(ss, 2);
        ss += __shfl_xor(ss, 4);
        ss += __shfl_xor(ss, 8);
        const float inv = 1.f / ss;
        if (m < 8) {
            __fp16* wp = &aW[s][(u * 8 + m) * 136];
#pragma unroll
            for (int t = 0; t < 7; ++t)
                wp[(u + t) * 16 + n16] = (__fp16)(lv[t] * inv);
        }
    }
    __syncthreads();

    // ---- Phase B: PV, pair-cooperative (wave does 4 tn c-tiles) ----
    uint4 pA[4];
#pragma unroll
    for (int kc = 0; kc < 4; ++kc)
        pA[kc] = *(const uint4*)(&aW[s][n16 * 136 + kc * 32 + quad * 8]);
#pragma unroll
    for (int tt = 0; tt < 4; ++tt) {
        const int tn = u * 4 + tt;
        f4_t acc = {0.f, 0.f, 0.f, 0.f};
#pragma unroll
        for (int kc = 0; kc < 4; ++kc) {
            const int kri = kc * 2 + (quad >> 1);
            const int ci0 = (quad & 1) * 8;
            const half8_t vB = *(const half8_t*)(
                vH + (tn * 16 + n16) * VP + (2 * s + kri) * 16 + ci0);
            acc = __builtin_amdgcn_mfma_f32_16x16x32_f16(
                __builtin_bit_cast(half8_t, pA[kc]), vB, acc, 0, 0, 0);
        }
        const int c = tn * 16 + n16;
        float* ob = out + (size_t)(b * 128 + c) * 4096;
#pragma unroll
        for (int i = 0; i < 4; ++i) {
            const int mm = quad * 4 + i;         // pair-row: <8 lower, >=8 upper
            ob[(h0 + 2 * s + (mm >> 3)) * 64 + w0 + (mm & 7)] = acc[i];
        }
    }
}

extern "C" void kernel_launch(void* const* d_in, const int* in_sizes, int n_in,
                              void* d_out, int out_size, void* d_ws, size_t ws_size,
                              hipStream_t stream) {
    const float* x    = (const float*)d_in[0];
    const float* wq   = (const float*)d_in[1];
    const float* wk   = (const float*)d_in[2];
    const float* wv   = (const float*)d_in[3];
    const float* relx = (const float*)d_in[4];
    const float* rely = (const float*)d_in[5];
    float* out = (float*)d_out;

    char* ws = (char*)d_ws;
    unsigned* qfb = (unsigned*)(ws);                 // 4 MB f16-packed [pos][c2]
    unsigned* kfb = (unsigned*)(ws + 0x400000);      // 4 MB
    unsigned* vfb = (unsigned*)(ws + 0x800000);      // 4 MB
    float*    bG  = (float*)   (ws + 0xC00000);      // 1 MB bias tables

    qkv_fused<<<dim3(768), 256, 0, stream>>>(x, wq, wk, wv, relx, rely,
                                             qfb, kfb, vfb, bG);
    attn_mfma<<<dim3(512), 256, 0, stream>>>(qfb, kfb, vfb, bG, out);
}